// Round 4
// baseline (192.016 us; speedup 1.0000x reference)
//
#include <hip/hip_runtime.h>
#include <hip/hip_bf16.h>

// Conv2d B=32 IC=128 112x112 -> OC=256, K=3, s=2, p=1 (OH=OW=56).
// Round 4: LDS-free xtrans. Thread owns one 8-channel output granule:
//   8 scalar f32 loads (wave-coalesced 256B along iw), pack bf16x8, uint4
//   store (block covers contiguous 16KB). No LDS, no barriers.
// k2/k3 unchanged from round 3 (attribution discipline).

#define B_    32
#define IC_   128
#define H_    112
#define W_    112
#define HW_   (H_ * W_)
#define OC_   256
#define OH_   56
#define OW_   56
#define HP    113
#define NPIX  (B_ * OH_ * OW_)          // 100352
#define XT_BYTES ((size_t)B_ * HP * HP * IC_ * 2)   // 104,603,648
#define WT_BYTES ((size_t)9 * OC_ * IC_ * 2)        // 589,824

typedef __attribute__((ext_vector_type(8))) short bf16x8;
typedef __attribute__((ext_vector_type(4))) float f32x4;

static __device__ __forceinline__ unsigned f2bf_u(float f) {
  union { float f; unsigned u; } v; v.f = f;
  return (v.u + 0x7FFF + ((v.u >> 16) & 1)) >> 16;   // RNE; inputs finite
}

// ---------------- k1: x -> padded channels-last bf16 (no LDS) ----------------
// Block: 1024 threads = 64 iwp x 16 icg. Reads: 8 scalar f32, each
// wave-coalesced (lanes = consecutive iw). Writes: uint4, block-contiguous.
__global__ __launch_bounds__(1024) void xtrans_kernel(
    const float* __restrict__ x, unsigned short* __restrict__ xt) {
  const int iwp = blockIdx.x * 64 + (threadIdx.x & 63);
  const int icg = threadIdx.x >> 6;        // 0..15
  const int ihp = blockIdx.y;              // 0..112 (0 = pad row)
  const int b   = blockIdx.z;
  if (iwp >= HP) return;

  uint4 v = {0u, 0u, 0u, 0u};
  if (ihp > 0 && iwp > 0) {
    const float* src = x + (size_t)b * IC_ * HW_ + (size_t)(icg * 8) * HW_
                         + (size_t)(ihp - 1) * W_ + (iwp - 1);
    unsigned u0 = f2bf_u(src[0 * HW_]);
    unsigned u1 = f2bf_u(src[1 * HW_]);
    unsigned u2 = f2bf_u(src[2 * HW_]);
    unsigned u3 = f2bf_u(src[3 * HW_]);
    unsigned u4 = f2bf_u(src[4 * HW_]);
    unsigned u5 = f2bf_u(src[5 * HW_]);
    unsigned u6 = f2bf_u(src[6 * HW_]);
    unsigned u7 = f2bf_u(src[7 * HW_]);
    v.x = u0 | (u1 << 16);
    v.y = u2 | (u3 << 16);
    v.z = u4 | (u5 << 16);
    v.w = u6 | (u7 << 16);
  }
  unsigned short* dst = xt + ((size_t)(b * HP + ihp)) * (HP * IC_)
                           + (size_t)iwp * IC_ + icg * 8;
  *reinterpret_cast<uint4*>(dst) = v;
}

// ---------------- k2: w -> wt[tap][oc][ic] bf16 ----------------
__global__ __launch_bounds__(256) void wtrans_kernel(
    const float* __restrict__ w, unsigned short* __restrict__ wt) {
  const int t  = blockIdx.x * 256 + threadIdx.x;   // 0..32767 == oc*128+ic
  const int oc = t >> 7;
  const int ic = t & 127;
  const float* ws = w + (size_t)t * 9;             // w[oc][ic][*]
#pragma unroll
  for (int tap = 0; tap < 9; ++tap)
    wt[((size_t)tap * OC_ + oc) * IC_ + ic] = (unsigned short)f2bf_u(ws[tap]);
}

// ---------------- k3: MFMA implicit GEMM (unchanged) ----------------
__global__ __launch_bounds__(256) void conv_mfma_kernel(
    const unsigned short* __restrict__ xt, const unsigned short* __restrict__ wt,
    const float* __restrict__ bias, float* __restrict__ out) {
  __shared__ short Ws[128 * 32];   // [oc_row][ic] 8 KiB
  __shared__ short Xs[128 * 32];   // [pix_row][ic] 8 KiB

  const int tid  = threadIdx.x;
  const int wav  = tid >> 6;
  const int lane = tid & 63;

  const int mt  = blockIdx.x & 1;      // oc tile (fast index: L2 reuse of X)
  const int pt  = blockIdx.x >> 1;     // pixel tile
  const int oc0 = mt * 128;
  const int p0  = pt * 128;

  const int l2 = lane >> 2;            // row within 16-row group
  const int lc = lane & 3;             // 16B chunk within 64B row
  const char* xsrc[2];
  const char* wsrc[2];
#pragma unroll
  for (int i = 0; i < 2; ++i) {
    const int pix = p0 + wav * 32 + i * 16 + l2;
    const int b   = pix / 3136;
    const int q   = pix - b * 3136;
    const int oh  = q / 56;
    const int ow  = q - oh * 56;
    const size_t e = (((size_t)b * HP + 2 * oh) * HP + 2 * ow) * IC_;
    xsrc[i] = reinterpret_cast<const char*>(xt) + e * 2 + lc * 16;
    const int ocr = oc0 + wav * 32 + i * 16 + l2;
    wsrc[i] = reinterpret_cast<const char*>(wt) + (size_t)ocr * IC_ * 2 + lc * 16;
  }
  char* xdst = reinterpret_cast<char*>(Xs) + wav * 2048;
  char* wdst = reinterpret_cast<char*>(Ws) + wav * 2048;

  const int wm  = wav >> 1;
  const int wn  = wav & 1;
  const int l15 = lane & 15;
  const int kg  = (lane >> 4) * 8;
  const short* wrow = Ws + ((wm * 64 + l15) * 32 + kg);
  const short* xrow = Xs + ((wn * 64 + l15) * 32 + kg);

  f32x4 acc[4][4] = {};

  for (int tap = 0; tap < 9; ++tap) {
    const int kh = tap / 3;
    const int kw = tap - kh * 3;
    const size_t xtap = ((size_t)(kh * HP + kw)) * IC_ * 2;
    const size_t wtap = (size_t)tap * OC_ * IC_ * 2;
#pragma unroll
    for (int icc = 0; icc < 4; ++icc) {
      const size_t xoff = xtap + (size_t)icc * 64;
      const size_t woff = wtap + (size_t)icc * 64;
      __syncthreads();
#pragma unroll
      for (int i = 0; i < 2; ++i) {
        __builtin_amdgcn_global_load_lds(
            (const __attribute__((address_space(1))) void*)(xsrc[i] + xoff),
            (__attribute__((address_space(3))) void*)(xdst + i * 1024), 16, 0, 0);
        __builtin_amdgcn_global_load_lds(
            (const __attribute__((address_space(1))) void*)(wsrc[i] + woff),
            (__attribute__((address_space(3))) void*)(wdst + i * 1024), 16, 0, 0);
      }
      __syncthreads();

      bf16x8 af[4], bfr[4];
#pragma unroll
      for (int mi = 0; mi < 4; ++mi)
        af[mi] = *reinterpret_cast<const bf16x8*>(wrow + mi * 16 * 32);
#pragma unroll
      for (int ni = 0; ni < 4; ++ni)
        bfr[ni] = *reinterpret_cast<const bf16x8*>(xrow + ni * 16 * 32);
#pragma unroll
      for (int mi = 0; mi < 4; ++mi)
#pragma unroll
        for (int ni = 0; ni < 4; ++ni)
          acc[mi][ni] = __builtin_amdgcn_mfma_f32_16x16x32_bf16(
              af[mi], bfr[ni], acc[mi][ni], 0, 0, 0);
    }
  }

#pragma unroll
  for (int mi = 0; mi < 4; ++mi) {
#pragma unroll
    for (int j = 0; j < 4; ++j) {
      const int oc = oc0 + wm * 64 + mi * 16 + (lane >> 4) * 4 + j;
      const float bv = bias[oc];
#pragma unroll
      for (int ni = 0; ni < 4; ++ni) {
        const int pix = p0 + wn * 64 + ni * 16 + l15;
        const int b   = pix / 3136;
        const int q   = pix - b * 3136;
        out[((size_t)b * OC_ + oc) * 3136 + q] = acc[mi][ni][j] + bv;
      }
    }
  }
}

// ---------------- fallback: fp32 direct conv ----------------
__global__ __launch_bounds__(256) void conv2d_f32_kernel(
    const float* __restrict__ x, const float* __restrict__ w,
    const float* __restrict__ bias, float* __restrict__ out) {
  __shared__ float wlds[IC_ * 9][8];
  const int b   = blockIdx.z;
  const int oc0 = blockIdx.y * 8;
  const float* wsrc = w + (size_t)oc0 * (IC_ * 9);
  for (int i = threadIdx.x; i < IC_ * 9 * 8; i += 256) {
    const int j = i / (IC_ * 9);
    const int t = i - j * (IC_ * 9);
    wlds[t][j] = wsrc[(size_t)j * (IC_ * 9) + t];
  }
  __syncthreads();
  const int p  = blockIdx.x * 256 + threadIdx.x;
  const int ow = p % OW_;
  const int oh = p / OW_;
  const bool pv = (oh < OH_);
  const int ih0 = 2 * oh - 1;
  const int iw0 = 2 * ow - 1;
  const float* xb = x + (size_t)b * IC_ * HW_ + (ptrdiff_t)ih0 * W_ + iw0;
  float acc[8];
#pragma unroll
  for (int j = 0; j < 8; ++j) acc[j] = 0.f;
  for (int ic = 0; ic < IC_; ++ic) {
    const float* xc = xb + (size_t)ic * HW_;
#pragma unroll
    for (int kh = 0; kh < 3; ++kh) {
      const bool hv = pv && ((ih0 + kh) >= 0);
#pragma unroll
      for (int kw = 0; kw < 3; ++kw) {
        const bool v = hv && ((iw0 + kw) >= 0);
        const float xv = v ? xc[kh * W_ + kw] : 0.f;
        const int t = ic * 9 + kh * 3 + kw;
        const float4 w0 = *reinterpret_cast<const float4*>(&wlds[t][0]);
        const float4 w1 = *reinterpret_cast<const float4*>(&wlds[t][4]);
        acc[0] = fmaf(xv, w0.x, acc[0]); acc[1] = fmaf(xv, w0.y, acc[1]);
        acc[2] = fmaf(xv, w0.z, acc[2]); acc[3] = fmaf(xv, w0.w, acc[3]);
        acc[4] = fmaf(xv, w1.x, acc[4]); acc[5] = fmaf(xv, w1.y, acc[5]);
        acc[6] = fmaf(xv, w1.z, acc[6]); acc[7] = fmaf(xv, w1.w, acc[7]);
      }
    }
  }
  if (pv) {
#pragma unroll
    for (int j = 0; j < 8; ++j)
      out[(((size_t)(b * OC_ + oc0 + j)) * OH_ + oh) * OW_ + ow] =
          acc[j] + bias[oc0 + j];
  }
}

extern "C" void kernel_launch(void* const* d_in, const int* in_sizes, int n_in,
                              void* d_out, int out_size, void* d_ws, size_t ws_size,
                              hipStream_t stream) {
  const float* x    = (const float*)d_in[0];
  const float* w    = (const float*)d_in[1];
  const float* bias = (const float*)d_in[2];
  float* out        = (float*)d_out;

  if (ws_size >= XT_BYTES + WT_BYTES) {
    unsigned short* xt  = (unsigned short*)d_ws;
    unsigned short* wtp = (unsigned short*)((char*)d_ws + XT_BYTES);
    xtrans_kernel<<<dim3(2, HP, B_), 1024, 0, stream>>>(x, xt);
    wtrans_kernel<<<128, 256, 0, stream>>>(w, wtp);
    conv_mfma_kernel<<<(NPIX / 128) * 2, 256, 0, stream>>>(xt, wtp, bias, out);
  } else {
    conv2d_f32_kernel<<<dim3(13, OC_ / 8, B_), 256, 0, stream>>>(x, w, bias, out);
  }
}

// Round 6
// 157.158 us; speedup vs baseline: 1.2218x; 1.2218x over previous
//
#include <hip/hip_runtime.h>
#include <hip/hip_bf16.h>

// Conv2d B=32 IC=128 112x112 -> OC=256, K=3, s=2, p=1 (OH=OW=56).
// Round 6: round-5 structure with the XCD-swizzle bijectivity bug fixed:
//   grid is 1568 blocks (784 pixel-tiles x 2 oc-tiles) -> chunk = 1568/8 = 196
//   (was 98: mapped [0,1568)->[0,882), half the tiles never computed).
//   wgid = (bid&7)*196 + (bid>>3): bijective; 196 even keeps mt-pairs on XCD.
// k1 xtrans: round-3 LDS version (measured ~82us). k3: 2-phase dbuf pipeline.

#define B_    32
#define IC_   128
#define H_    112
#define W_    112
#define HW_   (H_ * W_)
#define OC_   256
#define OH_   56
#define OW_   56
#define HP    113
#define NPIX  (B_ * OH_ * OW_)          // 100352
#define XT_BYTES ((size_t)B_ * HP * HP * IC_ * 2)   // 104,603,648
#define WT_BYTES ((size_t)9 * OC_ * IC_ * 2)        // 589,824

typedef __attribute__((ext_vector_type(8))) short bf16x8;
typedef __attribute__((ext_vector_type(4))) float f32x4;

static __device__ __forceinline__ unsigned f2bf_u(float f) {
  union { float f; unsigned u; } v; v.f = f;
  return (v.u + 0x7FFF + ((v.u >> 16) & 1)) >> 16;   // RNE; inputs finite
}

// ---------------- k1: x -> padded channels-last bf16 (round-3 version) ------
__global__ __launch_bounds__(256) void xtrans_kernel(
    const float* __restrict__ x, unsigned short* __restrict__ xt) {
  __shared__ unsigned short lds[128 * 128];   // 32 KiB, row stride 128 ush
  const int ihp = blockIdx.x;                 // 0..112 (0 = zero pad row)
  const int b   = blockIdx.y;
  const int tid = threadIdx.x;

  if (ihp > 0) {
    const float* xp = x + (size_t)b * IC_ * HW_ + (size_t)(ihp - 1) * W_;
#pragma unroll
    for (int it = 0; it < 16; ++it) {
      const int i  = tid + it * 256;          // (ic, g) over 128 x 32
      const int ic = i >> 5;
      const int g  = i & 31;                  // 16B granule along iw
      if (g < 28) {
        const float4 v = *reinterpret_cast<const float4*>(
            xp + (size_t)ic * HW_ + g * 4);
        uint2 p;
        p.x = f2bf_u(v.x) | (f2bf_u(v.y) << 16);
        p.y = f2bf_u(v.z) | (f2bf_u(v.w) << 16);
        const int gs = g ^ (((ic >> 3) & 7) << 2);
        *reinterpret_cast<uint2*>(&lds[ic * 128 + gs * 4]) = p;
      }
    }
  }
  __syncthreads();

  unsigned short* xrow = xt + ((size_t)(b * HP + ihp)) * (HP * IC_);
  const bool live = (ihp > 0);
#pragma unroll
  for (int it = 0; it < 8; ++it) {
    const int e = tid + it * 256;             // (iwp, icg) over 113 x 16
    if (e >= HP * 16) break;
    const int iwp = e >> 4;
    const int icg = e & 15;
    uint4 v = {0u, 0u, 0u, 0u};
    if (live && iwp > 0) {
      const int iw  = iwp - 1;
      const int col = ((iw >> 2) ^ ((icg & 7) << 2)) * 4 + (iw & 3);
      const int r0  = icg * 8;
      unsigned u0 = lds[(r0 + 0) * 128 + col];
      unsigned u1 = lds[(r0 + 1) * 128 + col];
      unsigned u2 = lds[(r0 + 2) * 128 + col];
      unsigned u3 = lds[(r0 + 3) * 128 + col];
      unsigned u4 = lds[(r0 + 4) * 128 + col];
      unsigned u5 = lds[(r0 + 5) * 128 + col];
      unsigned u6 = lds[(r0 + 6) * 128 + col];
      unsigned u7 = lds[(r0 + 7) * 128 + col];
      v.x = u0 | (u1 << 16);
      v.y = u2 | (u3 << 16);
      v.z = u4 | (u5 << 16);
      v.w = u6 | (u7 << 16);
    }
    *reinterpret_cast<uint4*>(xrow + iwp * IC_ + icg * 8) = v;
  }
}

// ---------------- k2: w -> wt[tap][oc][ic] bf16 ----------------
__global__ __launch_bounds__(256) void wtrans_kernel(
    const float* __restrict__ w, unsigned short* __restrict__ wt) {
  const int t  = blockIdx.x * 256 + threadIdx.x;   // 0..32767 == oc*128+ic
  const int oc = t >> 7;
  const int ic = t & 127;
  const float* ws = w + (size_t)t * 9;             // w[oc][ic][*]
#pragma unroll
  for (int tap = 0; tap < 9; ++tap)
    wt[((size_t)tap * OC_ + oc) * IC_ + ic] = (unsigned short)f2bf_u(ws[tap]);
}

// ---------------- k3: MFMA implicit GEMM, 2-phase dbuf + XCD swizzle --------
__global__ __launch_bounds__(256) void conv_mfma_kernel(
    const unsigned short* __restrict__ xt, const unsigned short* __restrict__ wt,
    const float* __restrict__ bias, float* __restrict__ out) {
  __shared__ short Ws[2][128 * 32];   // [buf][oc_row][ic]  2 x 8 KiB
  __shared__ short Xs[2][128 * 32];   // [buf][pix_row][ic] 2 x 8 KiB

  const int tid  = threadIdx.x;
  const int wav  = tid >> 6;
  const int lane = tid & 63;

  // T1: XCD-chunk swizzle over the FULL 1568-block grid: chunk = 1568/8 = 196.
  // bid = c*8 + x  ->  wgid = x*196 + c  (bijective; 196 even keeps mt-pairs).
  const int bid  = blockIdx.x;
  const int wgid = (bid & 7) * 196 + (bid >> 3);
  const int mt  = wgid & 1;            // oc tile (fast: shares pixel tile)
  const int pt  = wgid >> 1;           // pixel tile
  const int oc0 = mt * 128;
  const int p0  = pt * 128;

  // --- staging addresses: wave w stages rows [w*32, w*32+32) of each tile ---
  const int l2 = lane >> 2;            // row within 16-row group
  const int lc = lane & 3;             // 16B chunk within 64B row
  const char* xsrc[2];
  const char* wsrc[2];
#pragma unroll
  for (int i = 0; i < 2; ++i) {
    const int pix = p0 + wav * 32 + i * 16 + l2;
    const int b   = pix / 3136;
    const int q   = pix - b * 3136;
    const int oh  = q / 56;
    const int ow  = q - oh * 56;
    const size_t e = (((size_t)b * HP + 2 * oh) * HP + 2 * ow) * IC_;
    xsrc[i] = reinterpret_cast<const char*>(xt) + e * 2 + lc * 16;
    const int ocr = oc0 + wav * 32 + i * 16 + l2;
    wsrc[i] = reinterpret_cast<const char*>(wt) + (size_t)ocr * IC_ * 2 + lc * 16;
  }
  char* xdst = reinterpret_cast<char*>(&Xs[0][0]) + wav * 2048;
  char* wdst = reinterpret_cast<char*>(&Ws[0][0]) + wav * 2048;

  // --- fragment read bases ---
  const int wm  = wav >> 1;
  const int wn  = wav & 1;
  const int l15 = lane & 15;
  const int kg  = (lane >> 4) * 8;
  const short* wrow = &Ws[0][0] + ((wm * 64 + l15) * 32 + kg);
  const short* xrow = &Xs[0][0] + ((wn * 64 + l15) * 32 + kg);

  f32x4 acc[4][4] = {};

  auto stage = [&](int buf, int tap, int icc) {
    const int kh = tap / 3;
    const int kw = tap - kh * 3;
    const size_t xoff = ((size_t)(kh * HP + kw) * IC_ + icc * 32) * 2;
    const size_t woff = ((size_t)tap * OC_ * IC_ + icc * 32) * 2;
    char* xd = xdst + buf * (128 * 32 * 2);
    char* wd = wdst + buf * (128 * 32 * 2);
#pragma unroll
    for (int i = 0; i < 2; ++i) {
      __builtin_amdgcn_global_load_lds(
          (const __attribute__((address_space(1))) void*)(xsrc[i] + xoff),
          (__attribute__((address_space(3))) void*)(xd + i * 1024), 16, 0, 0);
      __builtin_amdgcn_global_load_lds(
          (const __attribute__((address_space(1))) void*)(wsrc[i] + woff),
          (__attribute__((address_space(3))) void*)(wd + i * 1024), 16, 0, 0);
    }
  };

  auto compute = [&](int buf) {
    const short* wr = wrow + buf * (128 * 32);
    const short* xr = xrow + buf * (128 * 32);
    bf16x8 af[4], bfr[4];
#pragma unroll
    for (int mi = 0; mi < 4; ++mi)
      af[mi] = *reinterpret_cast<const bf16x8*>(wr + mi * 16 * 32);
#pragma unroll
    for (int ni = 0; ni < 4; ++ni)
      bfr[ni] = *reinterpret_cast<const bf16x8*>(xr + ni * 16 * 32);
#pragma unroll
    for (int mi = 0; mi < 4; ++mi)
#pragma unroll
      for (int ni = 0; ni < 4; ++ni)
        acc[mi][ni] = __builtin_amdgcn_mfma_f32_16x16x32_bf16(
            af[mi], bfr[ni], acc[mi][ni], 0, 0, 0);
  };

  // Prologue: stage step (tap=0, icc=0) into buf0; barrier drains vmcnt.
  stage(0, 0, 0);
  __syncthreads();

  // 2-phase steady state: stage(next)->compute(cur)->barrier.
  // Buffer parity hand-unrolled (literal indices; 4 steps/tap restore parity).
  for (int tap = 0; tap < 9; ++tap) {
    const bool lt = (tap == 8);
    stage(1, tap, 1);  compute(0);  __syncthreads();
    stage(0, tap, 2);  compute(1);  __syncthreads();
    stage(1, tap, 3);  compute(0);  __syncthreads();
    if (!lt) { stage(0, tap + 1, 0); }
    compute(1);
    if (!lt) { __syncthreads(); }
  }

  // --- epilogue: D[oc][pix]; lanes sweep pixels -> coalesced ---
#pragma unroll
  for (int mi = 0; mi < 4; ++mi) {
#pragma unroll
    for (int j = 0; j < 4; ++j) {
      const int oc = oc0 + wm * 64 + mi * 16 + (lane >> 4) * 4 + j;
      const float bv = bias[oc];
#pragma unroll
      for (int ni = 0; ni < 4; ++ni) {
        const int pix = p0 + wn * 64 + ni * 16 + l15;
        const int b   = pix / 3136;
        const int q   = pix - b * 3136;
        out[((size_t)b * OC_ + oc) * 3136 + q] = acc[mi][ni][j] + bv;
      }
    }
  }
}

// ---------------- fallback: fp32 direct conv ----------------
__global__ __launch_bounds__(256) void conv2d_f32_kernel(
    const float* __restrict__ x, const float* __restrict__ w,
    const float* __restrict__ bias, float* __restrict__ out) {
  __shared__ float wlds[IC_ * 9][8];
  const int b   = blockIdx.z;
  const int oc0 = blockIdx.y * 8;
  const float* wsrc = w + (size_t)oc0 * (IC_ * 9);
  for (int i = threadIdx.x; i < IC_ * 9 * 8; i += 256) {
    const int j = i / (IC_ * 9);
    const int t = i - j * (IC_ * 9);
    wlds[t][j] = wsrc[(size_t)j * (IC_ * 9) + t];
  }
  __syncthreads();
  const int p  = blockIdx.x * 256 + threadIdx.x;
  const int ow = p % OW_;
  const int oh = p / OW_;
  const bool pv = (oh < OH_);
  const int ih0 = 2 * oh - 1;
  const int iw0 = 2 * ow - 1;
  const float* xb = x + (size_t)b * IC_ * HW_ + (ptrdiff_t)ih0 * W_ + iw0;
  float acc[8];
#pragma unroll
  for (int j = 0; j < 8; ++j) acc[j] = 0.f;
  for (int ic = 0; ic < IC_; ++ic) {
    const float* xc = xb + (size_t)ic * HW_;
#pragma unroll
    for (int kh = 0; kh < 3; ++kh) {
      const bool hv = pv && ((ih0 + kh) >= 0);
#pragma unroll
      for (int kw = 0; kw < 3; ++kw) {
        const bool v = hv && ((iw0 + kw) >= 0);
        const float xv = v ? xc[kh * W_ + kw] : 0.f;
        const int t = ic * 9 + kh * 3 + kw;
        const float4 w0 = *reinterpret_cast<const float4*>(&wlds[t][0]);
        const float4 w1 = *reinterpret_cast<const float4*>(&wlds[t][4]);
        acc[0] = fmaf(xv, w0.x, acc[0]); acc[1] = fmaf(xv, w0.y, acc[1]);
        acc[2] = fmaf(xv, w0.z, acc[2]); acc[3] = fmaf(xv, w0.w, acc[3]);
        acc[4] = fmaf(xv, w1.x, acc[4]); acc[5] = fmaf(xv, w1.y, acc[5]);
        acc[6] = fmaf(xv, w1.z, acc[6]); acc[7] = fmaf(xv, w1.w, acc[7]);
      }
    }
  }
  if (pv) {
#pragma unroll
    for (int j = 0; j < 8; ++j)
      out[(((size_t)(b * OC_ + oc0 + j)) * OH_ + oh) * OW_ + ow] =
          acc[j] + bias[oc0 + j];
  }
}

extern "C" void kernel_launch(void* const* d_in, const int* in_sizes, int n_in,
                              void* d_out, int out_size, void* d_ws, size_t ws_size,
                              hipStream_t stream) {
  const float* x    = (const float*)d_in[0];
  const float* w    = (const float*)d_in[1];
  const float* bias = (const float*)d_in[2];
  float* out        = (float*)d_out;

  if (ws_size >= XT_BYTES + WT_BYTES) {
    unsigned short* xt  = (unsigned short*)d_ws;
    unsigned short* wtp = (unsigned short*)((char*)d_ws + XT_BYTES);
    xtrans_kernel<<<dim3(HP, B_), 256, 0, stream>>>(x, xt);
    wtrans_kernel<<<128, 256, 0, stream>>>(w, wtp);
    conv_mfma_kernel<<<(NPIX / 128) * 2, 256, 0, stream>>>(xt, wtp, bias, out);
  } else {
    conv2d_f32_kernel<<<dim3(13, OC_ / 8, B_), 256, 0, stream>>>(x, w, bias, out);
  }
}